// Round 2
// baseline (1060.815 us; speedup 1.0000x reference)
//
#include <hip/hip_runtime.h>
#include <math.h>

#define B_   32
#define T_   64
#define D_   300
#define H_   256
#define G4H  1024   // 4*H
#define M_   64
#define C_   5

__device__ __forceinline__ float sigmoidf_(float x) { return 1.0f / (1.0f + expf(-x)); }
__device__ __forceinline__ float bf16lo_(unsigned int u) { return __uint_as_float(u << 16); }
__device__ __forceinline__ float bf16hi_(unsigned int u) { return __uint_as_float(u & 0xFFFF0000u); }
__device__ __forceinline__ unsigned short f2bf_(float v) {
    unsigned int u = __float_as_uint(v);
    u += 0x7FFFu + ((u >> 16) & 1u);   // RTNE
    return (unsigned short)(u >> 16);
}

// ---------------------------------------------------------------------------
// K0: zero the group-sync flags (must run every call; ws is not re-poisoned)
// ---------------------------------------------------------------------------
__global__ void k_zero(int* __restrict__ flags) {
    flags[threadIdx.x] = 0;   // 256 flags
}

// ---------------------------------------------------------------------------
// K1: length[b]
// ---------------------------------------------------------------------------
__global__ void k_length(const float* __restrict__ x, int* __restrict__ length) {
    const int b = blockIdx.x;
    const int t = threadIdx.x;  // 64 threads
    float mv = 0.f;
    const float* row = x + (size_t)(b * T_ + t) * D_;
    for (int d = 0; d < D_; ++d) mv = fmaxf(mv, fabsf(row[d]));
    unsigned long long m = __ballot(mv > 0.f);
    if (t == 0) length[b] = __popcll(m);
}

// ---------------------------------------------------------------------------
// K2: xw = concat-x part of the gate pre-activations (+ bias), fp32 GEMM
// ---------------------------------------------------------------------------
__global__ void k_xw(const float* __restrict__ x,
                     const float* __restrict__ Wfw, const float* __restrict__ bfw,
                     const float* __restrict__ Wbw, const float* __restrict__ bbw,
                     float* __restrict__ xw) {
    const int colTile = blockIdx.x;   // 0..15
    const int rowTile = blockIdx.y;   // 0..31
    const int dir     = blockIdx.z;   // 0..1
    const float* W    = dir ? Wbw : Wfw;
    const float* bias = dir ? bbw : bfw;

    __shared__ float As[64][33];
    __shared__ float Bs[32][64];

    const int tid = threadIdx.x;       // 256
    const int tr  = tid >> 4;
    const int tc  = tid & 15;
    const int row0 = rowTile * 64, col0 = colTile * 64;

    float acc[4][4] = {};

    for (int k0 = 0; k0 < 320; k0 += 32) {
        #pragma unroll
        for (int i = 0; i < 8; ++i) {
            int e = tid + i * 256;
            int r = e >> 5, kk = e & 31;
            int k = k0 + kk;
            As[r][kk] = (k < D_) ? x[(size_t)(row0 + r) * D_ + k] : 0.f;
        }
        #pragma unroll
        for (int i = 0; i < 8; ++i) {
            int e = tid + i * 256;
            int kk = e >> 6, cc = e & 63;
            int k = k0 + kk;
            Bs[kk][cc] = (k < D_) ? W[(size_t)k * G4H + col0 + cc] : 0.f;
        }
        __syncthreads();
        #pragma unroll
        for (int kk = 0; kk < 32; ++kk) {
            float a0 = As[tr * 4 + 0][kk], a1 = As[tr * 4 + 1][kk];
            float a2 = As[tr * 4 + 2][kk], a3 = As[tr * 4 + 3][kk];
            float b0 = Bs[kk][tc * 4 + 0], b1 = Bs[kk][tc * 4 + 1];
            float b2 = Bs[kk][tc * 4 + 2], b3 = Bs[kk][tc * 4 + 3];
            acc[0][0] += a0 * b0; acc[0][1] += a0 * b1; acc[0][2] += a0 * b2; acc[0][3] += a0 * b3;
            acc[1][0] += a1 * b0; acc[1][1] += a1 * b1; acc[1][2] += a1 * b2; acc[1][3] += a1 * b3;
            acc[2][0] += a2 * b0; acc[2][1] += a2 * b1; acc[2][2] += a2 * b2; acc[2][3] += a2 * b3;
            acc[3][0] += a3 * b0; acc[3][1] += a3 * b1; acc[3][2] += a3 * b2; acc[3][3] += a3 * b3;
        }
        __syncthreads();
    }

    #pragma unroll
    for (int i = 0; i < 4; ++i)
        #pragma unroll
        for (int j = 0; j < 4; ++j) {
            int col = col0 + tc * 4 + j;
            xw[(size_t)dir * 2048 * G4H + (size_t)(row0 + tr * 4 + i) * G4H + col] =
                acc[i][j] + bias[col];
        }
}

// ---------------------------------------------------------------------------
// K3: LSTM recurrence. 256 blocks = 64 groups (dir,b) x 4 column-slices.
// Each block holds its 256-column W_h slice in LDS (bf16, 128 KB).
// Per step, the 4 blocks of a group exchange 64-float h-slices via
// device-scope atomics + a release/acquire flag counter (4-deep slot ring).
// bid = js*64 + g  ->  bid%8 == g%8, so a group's blocks share an XCD.
// ---------------------------------------------------------------------------
__global__ void __launch_bounds__(512)
k_lstm(const float* __restrict__ Wfw, const float* __restrict__ Wbw,
       const float* __restrict__ xw, const int* __restrict__ length,
       float* __restrict__ lout, float* __restrict__ exbuf, int* __restrict__ flags) {
    const int bid = blockIdx.x;
    const int js  = bid >> 6;        // 0..3 column slice
    const int g   = bid & 63;        // group id
    const int dir = g >> 5;
    const int b   = g & 31;
    const int tid = threadIdx.x;     // 0..511

    __shared__ unsigned short Wl[256 * 256];  // [k][c] bf16, 128 KB
    __shared__ float hl[256];
    __shared__ float zred[8 * 256];
    __shared__ float zfin[256];

    // ---- stage W_h slice into LDS (once) ----
    const float* Wg = dir ? Wbw : Wfw;
    for (int idx = tid; idx < 256 * 256; idx += 512) {
        int k = idx >> 8, c = idx & 255;
        int gate = c >> 6, jj = c & 63;
        int colg = gate * 256 + js * 64 + jj;
        Wl[k * 256 + c] = f2bf_(Wg[(size_t)(D_ + k) * G4H + colg]);
    }
    if (tid < 256) hl[tid] = 0.f;
    const int len = length[b];
    __syncthreads();

    const int ks = tid >> 5;   // 0..15 : k-slice of 16
    const int cg = tid & 31;   // 0..31 : column octet
    const int l  = tid & 63;
    const int w  = tid >> 6;

    float cst = 0.f, hprev = 0.f;
    const uint4* Wl4 = (const uint4*)Wl;

    for (int s = 0; s < T_; ++s) {
        const int tt = dir ? (T_ - 1 - s) : s;

        // preload x-part of gate pre-activation for this thread's column
        float xv = 0.f;
        if (tid < 256) {
            int gate = tid >> 6, jj = tid & 63;
            int colg = gate * 256 + js * 64 + jj;
            xv = xw[((size_t)(dir * B_ + b) * T_ + tt) * G4H + colg];
        }

        // ---- dot: 8 columns x 16 k's per thread ----
        float acc[8] = {};
        #pragma unroll
        for (int i4 = 0; i4 < 4; ++i4) {
            float4 h4 = ((const float4*)hl)[ks * 4 + i4];
            #pragma unroll
            for (int ii = 0; ii < 4; ++ii) {
                int k = ks * 16 + i4 * 4 + ii;
                uint4 wv = Wl4[(k << 5) + cg];
                float hk = (&h4.x)[ii];
                acc[0] += bf16lo_(wv.x) * hk; acc[1] += bf16hi_(wv.x) * hk;
                acc[2] += bf16lo_(wv.y) * hk; acc[3] += bf16hi_(wv.y) * hk;
                acc[4] += bf16lo_(wv.z) * hk; acc[5] += bf16hi_(wv.z) * hk;
                acc[6] += bf16lo_(wv.w) * hk; acc[7] += bf16hi_(wv.w) * hk;
            }
        }
        // pair-reduce across the two 32-lane halves (ks, ks^1)
        #pragma unroll
        for (int i = 0; i < 8; ++i) acc[i] += __shfl_xor(acc[i], 32);
        if (l < 32) {
            float4* zp = (float4*)&zred[w * 256 + cg * 8];
            zp[0] = make_float4(acc[0], acc[1], acc[2], acc[3]);
            zp[1] = make_float4(acc[4], acc[5], acc[6], acc[7]);
        }
        __syncthreads();

        if (tid < 256) {
            float z = xv;
            #pragma unroll
            for (int ww = 0; ww < 8; ++ww) z += zred[ww * 256 + tid];
            zfin[tid] = z;
        }
        __syncthreads();

        // ---- gates for this block's 64 h-columns ----
        if (tid < 64) {
            float zi = zfin[tid], zj = zfin[64 + tid], zf = zfin[128 + tid], zo = zfin[192 + tid];
            float cn = sigmoidf_(zf + 1.0f) * cst + sigmoidf_(zi) * tanhf(zj);
            float hn = sigmoidf_(zo) * tanhf(cn);
            bool  msk = (tt < len);
            float ho  = msk ? hn : 0.f;
            float hk2 = msk ? hn : hprev;
            if (msk) cst = cn;
            hprev = hk2;
            int jglob = js * 64 + tid;
            lout[((size_t)(b * T_ + tt)) * (2 * H_) + dir * H_ + jglob] = ho;
            __hip_atomic_store(&exbuf[((size_t)g * 4 + (s & 3)) * 256 + jglob], hk2,
                               __ATOMIC_RELAXED, __HIP_MEMORY_SCOPE_AGENT);
        }
        __syncthreads();

        // ---- flag arrive + spin for all 4 slices ----
        if (tid == 0) {
            __threadfence();
            __hip_atomic_fetch_add(&flags[g * 4 + (s & 3)], 1,
                                   __ATOMIC_RELEASE, __HIP_MEMORY_SCOPE_AGENT);
            const int target = 4 * ((s >> 2) + 1);
            unsigned it = 0;
            while (__hip_atomic_load(&flags[g * 4 + (s & 3)],
                                     __ATOMIC_ACQUIRE, __HIP_MEMORY_SCOPE_AGENT) < target) {
                __builtin_amdgcn_s_sleep(2);
                if (++it > (1u << 26)) break;   // safety valve: wrong > wedged
            }
            __threadfence();
        }
        __syncthreads();

        // ---- reload full h for next step ----
        if (tid < 256)
            hl[tid] = __hip_atomic_load(&exbuf[((size_t)g * 4 + (s & 3)) * 256 + tid],
                                        __ATOMIC_RELAXED, __HIP_MEMORY_SCOPE_AGENT);
        __syncthreads();
    }
}

// ---------------------------------------------------------------------------
// K4: einsum partials. Grid (8 m-groups, 32 b). lout[b] staged in LDS once;
// ent streamed (the only mandatory 268 MB of HBM).
// ---------------------------------------------------------------------------
__global__ void __launch_bounds__(512)
k_einsum(const float* __restrict__ ent, const float* __restrict__ lout,
         float* __restrict__ partials) {
    const int mg = blockIdx.x;   // 0..7
    const int b  = blockIdx.y;   // 0..31
    const int d  = threadIdx.x;  // 0..511

    __shared__ float louts[T_][512];
    for (int t = 0; t < T_; ++t) louts[t][d] = lout[((size_t)(b * T_ + t)) * 512 + d];
    __syncthreads();

    for (int mi = 0; mi < 8; ++mi) {
        int m = mg * 8 + mi;
        const float* ep = ent + ((size_t)(m * B_ + b) * T_) * 512 + d;
        float acc = 0.f;
        #pragma unroll 4
        for (int t = 0; t < T_; ++t) acc += ep[(size_t)t * 512] * louts[t][d];
        partials[((size_t)m * B_ + b) * 512 + d] = acc;
    }
}

// ---------------------------------------------------------------------------
// K5: reduce partials over b -> output_f, then l1 = relu(of @ W1 + b1)
// ---------------------------------------------------------------------------
__global__ void k_l1(const float* __restrict__ partials, const float* __restrict__ W1,
                     const float* __restrict__ b1, float* __restrict__ l1) {
    const int m = blockIdx.x;
    const int j = threadIdx.x;  // 0..255
    __shared__ float of[512];
    for (int d = j; d < 512; d += 256) {
        float s = 0.f;
        #pragma unroll
        for (int cc = 0; cc < 32; ++cc) s += partials[((size_t)m * B_ + cc) * 512 + d];
        of[d] = s * (1.0f / T_);
    }
    __syncthreads();
    float z = b1[j];
    for (int k = 0; k < 512; ++k) z += of[k] * W1[(size_t)k * H_ + j];
    l1[(size_t)m * H_ + j] = fmaxf(z, 0.f);
}

// ---------------------------------------------------------------------------
// K6: head + loss
// ---------------------------------------------------------------------------
__global__ void k_head(const float* __restrict__ l1, const float* __restrict__ W2,
                       const float* __restrict__ b2, const int* __restrict__ labels,
                       float* __restrict__ out) {
    const int tid = threadIdx.x;  // 320 threads
    __shared__ float red[320];
    float term = 0.f;
    if (tid < 320) {
        int m = tid / 5, cc = tid % 5;
        float z = b2[cc];
        for (int k = 0; k < H_; ++k) z += l1[(size_t)m * H_ + k] * W2[(size_t)k * C_ + cc];
        float p = 1.f / (1.f + expf(-z));
        out[tid] = p;
        term = -(float)labels[tid] * logf(p);
    }
    red[tid] = term;
    __syncthreads();
    if (tid == 0) {
        float s = 0.f;
        for (int i = 0; i < 320; ++i) s += red[i];
        out[320] = s / (float)C_;
    }
}

// ---------------------------------------------------------------------------
extern "C" void kernel_launch(void* const* d_in, const int* in_sizes, int n_in,
                              void* d_out, int out_size, void* d_ws, size_t ws_size,
                              hipStream_t stream) {
    const float* x      = (const float*)d_in[0];
    const float* ent    = (const float*)d_in[1];
    const int*   labels = (const int*)d_in[2];
    const float* Wfw    = (const float*)d_in[3];
    const float* bfw    = (const float*)d_in[4];
    const float* Wbw    = (const float*)d_in[5];
    const float* bbw    = (const float*)d_in[6];
    const float* W1     = (const float*)d_in[7];
    const float* b1     = (const float*)d_in[8];
    const float* W2     = (const float*)d_in[9];
    const float* b2     = (const float*)d_in[10];
    float* out = (float*)d_out;

    // ws layout (same total footprint as round 1):
    float* ws     = (float*)d_ws;
    float* xw     = ws;                         // 4,194,304 floats (2*2048*1024)
    float* lout   = xw + 4194304;               // 1,048,576 floats
    float* exbuf  = lout + 1048576;             // 65,536 floats (64 groups * 4 slots * 256)
    int*   flags  = (int*)(exbuf + 65536);      // 256 ints
    float* l1     = (float*)(flags + 256);      // 16,384 floats
    int*   length = (int*)(l1 + 16384);         // 32 ints
    float* partials = xw;                       // alias: xw dead after k_lstm (64*32*512)

    k_zero<<<1, 256, 0, stream>>>(flags);
    k_length<<<32, 64, 0, stream>>>(x, length);
    k_xw<<<dim3(16, 32, 2), 256, 0, stream>>>(x, Wfw, bfw, Wbw, bbw, xw);
    k_lstm<<<256, 512, 0, stream>>>(Wfw, Wbw, xw, length, lout, exbuf, flags);
    k_einsum<<<dim3(8, 32), 512, 0, stream>>>(ent, lout, partials);
    k_l1<<<64, 256, 0, stream>>>(partials, W1, b1, l1);
    k_head<<<1, 320, 0, stream>>>(l1, W2, b2, labels, out);
}

// Round 3
// 653.552 us; speedup vs baseline: 1.6232x; 1.6232x over previous
//
#include <hip/hip_runtime.h>
#include <math.h>

#define B_   32
#define T_   64
#define D_   300
#define H_   256
#define G4H  1024   // 4*H
#define M_   64
#define C_   5

__device__ __forceinline__ float sigmoidf_(float x) { return 1.0f / (1.0f + expf(-x)); }
__device__ __forceinline__ float bf16lo_(unsigned int u) { return __uint_as_float(u << 16); }
__device__ __forceinline__ float bf16hi_(unsigned int u) { return __uint_as_float(u & 0xFFFF0000u); }
__device__ __forceinline__ unsigned short f2bf_(float v) {
    unsigned int u = __float_as_uint(v);
    u += 0x7FFFu + ((u >> 16) & 1u);   // RTNE
    return (unsigned short)(u >> 16);
}

#define FLAG_STRIDE 32   // ints; 128 B per writer -> one writer per cache line

// ---------------------------------------------------------------------------
// K0: zero the per-writer sequence flags (ws is not re-poisoned between calls)
// ---------------------------------------------------------------------------
__global__ void k_zero(int* __restrict__ flags) {
    const int n = 256 * FLAG_STRIDE;
    for (int i = threadIdx.x; i < n; i += 512) flags[i] = 0;
}

// ---------------------------------------------------------------------------
// K1: length[b]
// ---------------------------------------------------------------------------
__global__ void k_length(const float* __restrict__ x, int* __restrict__ length) {
    const int b = blockIdx.x;
    const int t = threadIdx.x;  // 64 threads
    float mv = 0.f;
    const float* row = x + (size_t)(b * T_ + t) * D_;
    for (int d = 0; d < D_; ++d) mv = fmaxf(mv, fabsf(row[d]));
    unsigned long long m = __ballot(mv > 0.f);
    if (t == 0) length[b] = __popcll(m);
}

// ---------------------------------------------------------------------------
// K2: xw = x-part of gate pre-activations (+ bias), fp32 GEMM
// ---------------------------------------------------------------------------
__global__ void k_xw(const float* __restrict__ x,
                     const float* __restrict__ Wfw, const float* __restrict__ bfw,
                     const float* __restrict__ Wbw, const float* __restrict__ bbw,
                     float* __restrict__ xw) {
    const int colTile = blockIdx.x;   // 0..15
    const int rowTile = blockIdx.y;   // 0..31
    const int dir     = blockIdx.z;   // 0..1
    const float* W    = dir ? Wbw : Wfw;
    const float* bias = dir ? bbw : bfw;

    __shared__ float As[64][33];
    __shared__ float Bs[32][64];

    const int tid = threadIdx.x;       // 256
    const int tr  = tid >> 4;
    const int tc  = tid & 15;
    const int row0 = rowTile * 64, col0 = colTile * 64;

    float acc[4][4] = {};

    for (int k0 = 0; k0 < 320; k0 += 32) {
        #pragma unroll
        for (int i = 0; i < 8; ++i) {
            int e = tid + i * 256;
            int r = e >> 5, kk = e & 31;
            int k = k0 + kk;
            As[r][kk] = (k < D_) ? x[(size_t)(row0 + r) * D_ + k] : 0.f;
        }
        #pragma unroll
        for (int i = 0; i < 8; ++i) {
            int e = tid + i * 256;
            int kk = e >> 6, cc = e & 63;
            int k = k0 + kk;
            Bs[kk][cc] = (k < D_) ? W[(size_t)k * G4H + col0 + cc] : 0.f;
        }
        __syncthreads();
        #pragma unroll
        for (int kk = 0; kk < 32; ++kk) {
            float a0 = As[tr * 4 + 0][kk], a1 = As[tr * 4 + 1][kk];
            float a2 = As[tr * 4 + 2][kk], a3 = As[tr * 4 + 3][kk];
            float b0 = Bs[kk][tc * 4 + 0], b1 = Bs[kk][tc * 4 + 1];
            float b2 = Bs[kk][tc * 4 + 2], b3 = Bs[kk][tc * 4 + 3];
            acc[0][0] += a0 * b0; acc[0][1] += a0 * b1; acc[0][2] += a0 * b2; acc[0][3] += a0 * b3;
            acc[1][0] += a1 * b0; acc[1][1] += a1 * b1; acc[1][2] += a1 * b2; acc[1][3] += a1 * b3;
            acc[2][0] += a2 * b0; acc[2][1] += a2 * b1; acc[2][2] += a2 * b2; acc[2][3] += a2 * b3;
            acc[3][0] += a3 * b0; acc[3][1] += a3 * b1; acc[3][2] += a3 * b2; acc[3][3] += a3 * b3;
        }
        __syncthreads();
    }

    #pragma unroll
    for (int i = 0; i < 4; ++i)
        #pragma unroll
        for (int j = 0; j < 4; ++j) {
            int col = col0 + tc * 4 + j;
            xw[(size_t)dir * 2048 * G4H + (size_t)(row0 + tr * 4 + i) * G4H + col] =
                acc[i][j] + bias[col];
        }
}

// ---------------------------------------------------------------------------
// K3: LSTM recurrence. 256 blocks = 64 groups (dir,b) x 4 column-slices.
// W_h slice resident in LDS (bf16, 128 KB). Cross-block h exchange via
// relaxed agent atomics + per-writer padded sequence flags (release/acquire).
// No RMW, no __threadfence. 2-slot data ring (member skew <= 1 step).
// ---------------------------------------------------------------------------
__global__ void __launch_bounds__(512)
k_lstm(const float* __restrict__ Wfw, const float* __restrict__ Wbw,
       const float* __restrict__ xw, const int* __restrict__ length,
       float* __restrict__ lout, float* __restrict__ exbuf, int* __restrict__ flags) {
    const int bid = blockIdx.x;
    const int js  = bid >> 6;        // 0..3 column slice
    const int g   = bid & 63;        // group id
    const int dir = g >> 5;
    const int b   = g & 31;
    const int tid = threadIdx.x;     // 0..511

    __shared__ unsigned short Wl[256 * 256];  // [k][c] bf16, 128 KB
    __shared__ float hl[256];
    __shared__ float zred[8 * 256];
    __shared__ float zfin[256];

    // ---- stage W_h slice into LDS (once) ----
    const float* Wg = dir ? Wbw : Wfw;
    for (int idx = tid; idx < 256 * 256; idx += 512) {
        int k = idx >> 8, c = idx & 255;
        int gate = c >> 6, jj = c & 63;
        int colg = gate * 256 + js * 64 + jj;
        Wl[k * 256 + c] = f2bf_(Wg[(size_t)(D_ + k) * G4H + colg]);
    }
    if (tid < 256) hl[tid] = 0.f;
    const int len = length[b];
    __syncthreads();

    const int ks = tid >> 5;   // 0..15 : k-slice of 16
    const int cg = tid & 31;   // 0..31 : column octet
    const int l  = tid & 63;
    const int w  = tid >> 6;

    float cst = 0.f, hprev = 0.f;
    const uint4* Wl4 = (const uint4*)Wl;

    for (int s = 0; s < T_; ++s) {
        const int tt = dir ? (T_ - 1 - s) : s;

        // x-part of gate pre-activation for this thread's column
        float xv = 0.f;
        if (tid < 256) {
            int gate = tid >> 6, jj = tid & 63;
            int colg = gate * 256 + js * 64 + jj;
            xv = xw[((size_t)(dir * B_ + b) * T_ + tt) * G4H + colg];
        }

        // ---- dot: 8 columns x 16 k's per thread ----
        float acc[8] = {};
        #pragma unroll
        for (int i4 = 0; i4 < 4; ++i4) {
            float4 h4 = ((const float4*)hl)[ks * 4 + i4];
            #pragma unroll
            for (int ii = 0; ii < 4; ++ii) {
                int k = ks * 16 + i4 * 4 + ii;
                uint4 wv = Wl4[(k << 5) + cg];
                float hk = (&h4.x)[ii];
                acc[0] += bf16lo_(wv.x) * hk; acc[1] += bf16hi_(wv.x) * hk;
                acc[2] += bf16lo_(wv.y) * hk; acc[3] += bf16hi_(wv.y) * hk;
                acc[4] += bf16lo_(wv.z) * hk; acc[5] += bf16hi_(wv.z) * hk;
                acc[6] += bf16lo_(wv.w) * hk; acc[7] += bf16hi_(wv.w) * hk;
            }
        }
        #pragma unroll
        for (int i = 0; i < 8; ++i) acc[i] += __shfl_xor(acc[i], 32);
        if (l < 32) {
            float4* zp = (float4*)&zred[w * 256 + cg * 8];
            zp[0] = make_float4(acc[0], acc[1], acc[2], acc[3]);
            zp[1] = make_float4(acc[4], acc[5], acc[6], acc[7]);
        }
        __syncthreads();

        if (tid < 256) {
            float z = xv;
            #pragma unroll
            for (int ww = 0; ww < 8; ++ww) z += zred[ww * 256 + tid];
            zfin[tid] = z;
        }
        __syncthreads();

        // ---- gates for this block's 64 h-columns; publish h slice ----
        if (tid < 64) {
            float zi = zfin[tid], zj = zfin[64 + tid], zf = zfin[128 + tid], zo = zfin[192 + tid];
            float cn = sigmoidf_(zf + 1.0f) * cst + sigmoidf_(zi) * tanhf(zj);
            float hn = sigmoidf_(zo) * tanhf(cn);
            bool  msk = (tt < len);
            float ho  = msk ? hn : 0.f;
            float hk2 = msk ? hn : hprev;
            if (msk) cst = cn;
            hprev = hk2;
            int jglob = js * 64 + tid;
            lout[((size_t)(b * T_ + tt)) * (2 * H_) + dir * H_ + jglob] = ho;
            __hip_atomic_store(&exbuf[((size_t)g * 2 + (s & 1)) * 256 + jglob], hk2,
                               __ATOMIC_RELAXED, __HIP_MEMORY_SCOPE_AGENT);
        }
        __syncthreads();   // drains vmcnt: all data stores done before flag

        // ---- publish sequence flag (release), poll peers (acquire) ----
        if (tid == 0)
            __hip_atomic_store(&flags[bid * FLAG_STRIDE], s + 1,
                               __ATOMIC_RELEASE, __HIP_MEMORY_SCOPE_AGENT);
        if (tid < 64) {
            unsigned it = 0;
            for (;;) {
                int f = 0x7FFFFFFF;
                if (tid < 4)
                    f = __hip_atomic_load(&flags[(tid * 64 + g) * FLAG_STRIDE],
                                          __ATOMIC_ACQUIRE, __HIP_MEMORY_SCOPE_AGENT);
                if (__all(f >= s + 1)) break;
                __builtin_amdgcn_s_sleep(1);
                if (++it > (1u << 24)) break;   // safety valve: wrong > wedged
            }
        }
        __syncthreads();

        // ---- reload full h for next step ----
        if (tid < 256)
            hl[tid] = __hip_atomic_load(&exbuf[((size_t)g * 2 + (s & 1)) * 256 + tid],
                                        __ATOMIC_RELAXED, __HIP_MEMORY_SCOPE_AGENT);
        __syncthreads();
    }
}

// ---------------------------------------------------------------------------
// K4: einsum partials. Grid (8 m-groups, 32 b). lout[b] staged in LDS once;
// ent streamed (the mandatory 268 MB of HBM).
// ---------------------------------------------------------------------------
__global__ void __launch_bounds__(512)
k_einsum(const float* __restrict__ ent, const float* __restrict__ lout,
         float* __restrict__ partials) {
    const int mg = blockIdx.x;   // 0..7
    const int b  = blockIdx.y;   // 0..31
    const int d  = threadIdx.x;  // 0..511

    __shared__ float louts[T_][512];
    for (int t = 0; t < T_; ++t) louts[t][d] = lout[((size_t)(b * T_ + t)) * 512 + d];
    __syncthreads();

    for (int mi = 0; mi < 8; ++mi) {
        int m = mg * 8 + mi;
        const float* ep = ent + ((size_t)(m * B_ + b) * T_) * 512 + d;
        float acc = 0.f;
        #pragma unroll 4
        for (int t = 0; t < T_; ++t) acc += ep[(size_t)t * 512] * louts[t][d];
        partials[((size_t)m * B_ + b) * 512 + d] = acc;
    }
}

// ---------------------------------------------------------------------------
// K5: reduce partials over b -> output_f, then l1 = relu(of @ W1 + b1)
// ---------------------------------------------------------------------------
__global__ void k_l1(const float* __restrict__ partials, const float* __restrict__ W1,
                     const float* __restrict__ b1, float* __restrict__ l1) {
    const int m = blockIdx.x;
    const int j = threadIdx.x;  // 0..255
    __shared__ float of[512];
    for (int d = j; d < 512; d += 256) {
        float s = 0.f;
        #pragma unroll
        for (int cc = 0; cc < 32; ++cc) s += partials[((size_t)m * B_ + cc) * 512 + d];
        of[d] = s * (1.0f / T_);
    }
    __syncthreads();
    float z = b1[j];
    for (int k = 0; k < 512; ++k) z += of[k] * W1[(size_t)k * H_ + j];
    l1[(size_t)m * H_ + j] = fmaxf(z, 0.f);
}

// ---------------------------------------------------------------------------
// K6: head + loss
// ---------------------------------------------------------------------------
__global__ void k_head(const float* __restrict__ l1, const float* __restrict__ W2,
                       const float* __restrict__ b2, const int* __restrict__ labels,
                       float* __restrict__ out) {
    const int tid = threadIdx.x;  // 320 threads
    __shared__ float red[320];
    float term = 0.f;
    if (tid < 320) {
        int m = tid / 5, cc = tid % 5;
        float z = b2[cc];
        for (int k = 0; k < H_; ++k) z += l1[(size_t)m * H_ + k] * W2[(size_t)k * C_ + cc];
        float p = 1.f / (1.f + expf(-z));
        out[tid] = p;
        term = -(float)labels[tid] * logf(p);
    }
    red[tid] = term;
    __syncthreads();
    if (tid == 0) {
        float s = 0.f;
        for (int i = 0; i < 320; ++i) s += red[i];
        out[320] = s / (float)C_;
    }
}

// ---------------------------------------------------------------------------
extern "C" void kernel_launch(void* const* d_in, const int* in_sizes, int n_in,
                              void* d_out, int out_size, void* d_ws, size_t ws_size,
                              hipStream_t stream) {
    const float* x      = (const float*)d_in[0];
    const float* ent    = (const float*)d_in[1];
    const int*   labels = (const int*)d_in[2];
    const float* Wfw    = (const float*)d_in[3];
    const float* bfw    = (const float*)d_in[4];
    const float* Wbw    = (const float*)d_in[5];
    const float* bbw    = (const float*)d_in[6];
    const float* W1     = (const float*)d_in[7];
    const float* b1     = (const float*)d_in[8];
    const float* W2     = (const float*)d_in[9];
    const float* b2     = (const float*)d_in[10];
    float* out = (float*)d_out;

    float* ws     = (float*)d_ws;
    float* xw     = ws;                         // 4,194,304 floats
    float* lout   = xw + 4194304;               // 1,048,576 floats
    float* exbuf  = lout + 1048576;             // 32,768 floats (64 groups * 2 slots * 256)
    int*   flags  = (int*)(exbuf + 32768);      // 256 * FLAG_STRIDE ints (32 KB)
    float* l1     = (float*)(flags + 256 * FLAG_STRIDE);  // 16,384 floats
    int*   length = (int*)(l1 + 16384);         // 32 ints
    float* partials = xw;                       // alias: xw dead after k_lstm

    k_zero<<<1, 512, 0, stream>>>(flags);
    k_length<<<32, 64, 0, stream>>>(x, length);
    k_xw<<<dim3(16, 32, 2), 256, 0, stream>>>(x, Wfw, bfw, Wbw, bbw, xw);
    k_lstm<<<256, 512, 0, stream>>>(Wfw, Wbw, xw, length, lout, exbuf, flags);
    k_einsum<<<dim3(8, 32), 512, 0, stream>>>(ent, lout, partials);
    k_l1<<<64, 256, 0, stream>>>(partials, W1, b1, l1);
    k_head<<<1, 320, 0, stream>>>(l1, W2, b2, labels, out);
}

// Round 4
// 394.773 us; speedup vs baseline: 2.6872x; 1.6555x over previous
//
#include <hip/hip_runtime.h>
#include <math.h>

#define B_   32
#define T_   64
#define D_   300
#define H_   256
#define G4H  1024   // 4*H
#define M_   64
#define C_   5

__device__ __forceinline__ float sigmoidf_(float x) { return 1.0f / (1.0f + expf(-x)); }
__device__ __forceinline__ float bf16lo_(unsigned int u) { return __uint_as_float(u << 16); }
__device__ __forceinline__ float bf16hi_(unsigned int u) { return __uint_as_float(u & 0xFFFF0000u); }
__device__ __forceinline__ unsigned short f2bf_(float v) {
    unsigned int u = __float_as_uint(v);
    u += 0x7FFFu + ((u >> 16) & 1u);   // RTNE
    return (unsigned short)(u >> 16);
}

// ---------------------------------------------------------------------------
// K1: length[b]
// ---------------------------------------------------------------------------
__global__ void k_length(const float* __restrict__ x, int* __restrict__ length) {
    const int b = blockIdx.x;
    const int t = threadIdx.x;  // 64 threads
    float mv = 0.f;
    const float* row = x + (size_t)(b * T_ + t) * D_;
    for (int d = 0; d < D_; ++d) mv = fmaxf(mv, fabsf(row[d]));
    unsigned long long m = __ballot(mv > 0.f);
    if (t == 0) length[b] = __popcll(m);
}

// ---------------------------------------------------------------------------
// K2: xw = x-part of gate pre-activations (+ bias), fp32 GEMM
// ---------------------------------------------------------------------------
__global__ void k_xw(const float* __restrict__ x,
                     const float* __restrict__ Wfw, const float* __restrict__ bfw,
                     const float* __restrict__ Wbw, const float* __restrict__ bbw,
                     float* __restrict__ xw) {
    const int colTile = blockIdx.x;   // 0..15
    const int rowTile = blockIdx.y;   // 0..31
    const int dir     = blockIdx.z;   // 0..1
    const float* W    = dir ? Wbw : Wfw;
    const float* bias = dir ? bbw : bfw;

    __shared__ float As[64][33];
    __shared__ float Bs[32][64];

    const int tid = threadIdx.x;       // 256
    const int tr  = tid >> 4;
    const int tc  = tid & 15;
    const int row0 = rowTile * 64, col0 = colTile * 64;

    float acc[4][4] = {};

    for (int k0 = 0; k0 < 320; k0 += 32) {
        #pragma unroll
        for (int i = 0; i < 8; ++i) {
            int e = tid + i * 256;
            int r = e >> 5, kk = e & 31;
            int k = k0 + kk;
            As[r][kk] = (k < D_) ? x[(size_t)(row0 + r) * D_ + k] : 0.f;
        }
        #pragma unroll
        for (int i = 0; i < 8; ++i) {
            int e = tid + i * 256;
            int kk = e >> 6, cc = e & 63;
            int k = k0 + kk;
            Bs[kk][cc] = (k < D_) ? W[(size_t)k * G4H + col0 + cc] : 0.f;
        }
        __syncthreads();
        #pragma unroll
        for (int kk = 0; kk < 32; ++kk) {
            float a0 = As[tr * 4 + 0][kk], a1 = As[tr * 4 + 1][kk];
            float a2 = As[tr * 4 + 2][kk], a3 = As[tr * 4 + 3][kk];
            float b0 = Bs[kk][tc * 4 + 0], b1 = Bs[kk][tc * 4 + 1];
            float b2 = Bs[kk][tc * 4 + 2], b3 = Bs[kk][tc * 4 + 3];
            acc[0][0] += a0 * b0; acc[0][1] += a0 * b1; acc[0][2] += a0 * b2; acc[0][3] += a0 * b3;
            acc[1][0] += a1 * b0; acc[1][1] += a1 * b1; acc[1][2] += a1 * b2; acc[1][3] += a1 * b3;
            acc[2][0] += a2 * b0; acc[2][1] += a2 * b1; acc[2][2] += a2 * b2; acc[2][3] += a2 * b3;
            acc[3][0] += a3 * b0; acc[3][1] += a3 * b1; acc[3][2] += a3 * b2; acc[3][3] += a3 * b3;
        }
        __syncthreads();
    }

    #pragma unroll
    for (int i = 0; i < 4; ++i)
        #pragma unroll
        for (int j = 0; j < 4; ++j) {
            int col = col0 + tc * 4 + j;
            xw[(size_t)dir * 2048 * G4H + (size_t)(row0 + tr * 4 + i) * G4H + col] =
                acc[i][j] + bias[col];
        }
}

// ---------------------------------------------------------------------------
// K3: LSTM recurrence. 256 blocks = 64 groups (dir,b) x 4 column-slices.
// W_h slice resident in LDS (bf16, 128 KB). Cross-block h exchange:
// tagged-data protocol — writers force the fp32 LSB to the ring-cycle
// parity; readers poll their word (relaxed agent) until the LSB matches.
// Single L3 trip, no flags, no fences, no acquire-invalidate storm.
// 4-slot ring; member skew <= 1 step, reuse distance 4 -> safe.
// Stale data (prev cycle / prev call / 0xAA poison) has opposite LSB.
// ---------------------------------------------------------------------------
__global__ void __launch_bounds__(512)
k_lstm(const float* __restrict__ Wfw, const float* __restrict__ Wbw,
       const float* __restrict__ xw, const int* __restrict__ length,
       float* __restrict__ lout, unsigned* __restrict__ exbuf) {
    const int bid = blockIdx.x;
    const int js  = bid >> 6;        // 0..3 column slice
    const int g   = bid & 63;        // group id
    const int dir = g >> 5;
    const int b   = g & 31;
    const int tid = threadIdx.x;     // 0..511

    __shared__ unsigned short Wl[256 * 256];  // [k][c] bf16, 128 KB
    __shared__ float hl[256];
    __shared__ float zred[8 * 256];
    __shared__ float zfin[256];

    // ---- stage W_h slice into LDS (once) ----
    const float* Wg = dir ? Wbw : Wfw;
    for (int idx = tid; idx < 256 * 256; idx += 512) {
        int k = idx >> 8, c = idx & 255;
        int gate = c >> 6, jj = c & 63;
        int colg = gate * 256 + js * 64 + jj;
        Wl[k * 256 + c] = f2bf_(Wg[(size_t)(D_ + k) * G4H + colg]);
    }
    if (tid < 256) hl[tid] = 0.f;
    const int len = length[b];
    __syncthreads();

    const int ks = tid >> 5;   // 0..15 : k-slice of 16
    const int cg = tid & 31;   // 0..31 : column octet
    const int l  = tid & 63;
    const int w  = tid >> 6;

    float cst = 0.f, hprev = 0.f;
    const uint4* Wl4 = (const uint4*)Wl;

    for (int s = 0; s < T_; ++s) {
        const int tt = dir ? (T_ - 1 - s) : s;
        const unsigned tag = ((unsigned)(s >> 2) & 1u) ^ 1u;   // ring-cycle parity
        const size_t slotBase = ((size_t)g * 4 + (s & 3)) * 256;

        // x-part of gate pre-activation for this thread's column
        float xv = 0.f;
        if (tid < 256) {
            int gate = tid >> 6, jj = tid & 63;
            int colg = gate * 256 + js * 64 + jj;
            xv = xw[((size_t)(dir * B_ + b) * T_ + tt) * G4H + colg];
        }

        // ---- dot: 8 columns x 16 k's per thread ----
        float acc[8] = {};
        #pragma unroll
        for (int i4 = 0; i4 < 4; ++i4) {
            float4 h4 = ((const float4*)hl)[ks * 4 + i4];
            #pragma unroll
            for (int ii = 0; ii < 4; ++ii) {
                int k = ks * 16 + i4 * 4 + ii;
                uint4 wv = Wl4[(k << 5) + cg];
                float hk = (&h4.x)[ii];
                acc[0] += bf16lo_(wv.x) * hk; acc[1] += bf16hi_(wv.x) * hk;
                acc[2] += bf16lo_(wv.y) * hk; acc[3] += bf16hi_(wv.y) * hk;
                acc[4] += bf16lo_(wv.z) * hk; acc[5] += bf16hi_(wv.z) * hk;
                acc[6] += bf16lo_(wv.w) * hk; acc[7] += bf16hi_(wv.w) * hk;
            }
        }
        #pragma unroll
        for (int i = 0; i < 8; ++i) acc[i] += __shfl_xor(acc[i], 32);
        if (l < 32) {
            float4* zp = (float4*)&zred[w * 256 + cg * 8];
            zp[0] = make_float4(acc[0], acc[1], acc[2], acc[3]);
            zp[1] = make_float4(acc[4], acc[5], acc[6], acc[7]);
        }
        __syncthreads();

        if (tid < 256) {
            float z = xv;
            #pragma unroll
            for (int ww = 0; ww < 8; ++ww) z += zred[ww * 256 + tid];
            zfin[tid] = z;
        }
        __syncthreads();

        // ---- gates for this block's 64 h-columns; publish tagged h slice ----
        if (tid < 64) {
            float zi = zfin[tid], zj = zfin[64 + tid], zf = zfin[128 + tid], zo = zfin[192 + tid];
            float cn = sigmoidf_(zf + 1.0f) * cst + sigmoidf_(zi) * tanhf(zj);
            float hn = sigmoidf_(zo) * tanhf(cn);
            bool  msk = (tt < len);
            float ho  = msk ? hn : 0.f;
            float hk2 = msk ? hn : hprev;
            if (msk) cst = cn;
            hprev = hk2;
            int jglob = js * 64 + tid;
            lout[((size_t)(b * T_ + tt)) * (2 * H_) + dir * H_ + jglob] = ho;
            hl[jglob] = hk2;   // own slice straight into LDS
            unsigned bits = (__float_as_uint(hk2) & ~1u) | tag;
            __hip_atomic_store(&exbuf[slotBase + jglob], bits,
                               __ATOMIC_RELAXED, __HIP_MEMORY_SCOPE_AGENT);
        }

        // ---- poll peers' tagged words (single L3 trip, relaxed) ----
        if (tid < 256 && (tid >> 6) != js) {
            unsigned v; unsigned it = 0;
            for (;;) {
                v = __hip_atomic_load(&exbuf[slotBase + tid],
                                      __ATOMIC_RELAXED, __HIP_MEMORY_SCOPE_AGENT);
                if ((v & 1u) == tag) break;
                __builtin_amdgcn_s_sleep(1);
                if (++it > (1u << 20)) break;   // safety valve: wrong > wedged
            }
            hl[tid] = __uint_as_float(v);
        }
        __syncthreads();
    }
}

// ---------------------------------------------------------------------------
// K4: einsum partials. Grid (8 m-groups, 32 b). lout[b] staged in LDS once;
// ent streamed (the mandatory 268 MB of HBM).
// ---------------------------------------------------------------------------
__global__ void __launch_bounds__(512)
k_einsum(const float* __restrict__ ent, const float* __restrict__ lout,
         float* __restrict__ partials) {
    const int mg = blockIdx.x;   // 0..7
    const int b  = blockIdx.y;   // 0..31
    const int d  = threadIdx.x;  // 0..511

    __shared__ float louts[T_][512];
    for (int t = 0; t < T_; ++t) louts[t][d] = lout[((size_t)(b * T_ + t)) * 512 + d];
    __syncthreads();

    for (int mi = 0; mi < 8; ++mi) {
        int m = mg * 8 + mi;
        const float* ep = ent + ((size_t)(m * B_ + b) * T_) * 512 + d;
        float acc = 0.f;
        #pragma unroll 4
        for (int t = 0; t < T_; ++t) acc += ep[(size_t)t * 512] * louts[t][d];
        partials[((size_t)m * B_ + b) * 512 + d] = acc;
    }
}

// ---------------------------------------------------------------------------
// K5: reduce partials over b -> output_f, then l1 = relu(of @ W1 + b1)
// ---------------------------------------------------------------------------
__global__ void k_l1(const float* __restrict__ partials, const float* __restrict__ W1,
                     const float* __restrict__ b1, float* __restrict__ l1) {
    const int m = blockIdx.x;
    const int j = threadIdx.x;  // 0..255
    __shared__ float of[512];
    for (int d = j; d < 512; d += 256) {
        float s = 0.f;
        #pragma unroll
        for (int cc = 0; cc < 32; ++cc) s += partials[((size_t)m * B_ + cc) * 512 + d];
        of[d] = s * (1.0f / T_);
    }
    __syncthreads();
    float z = b1[j];
    for (int k = 0; k < 512; ++k) z += of[k] * W1[(size_t)k * H_ + j];
    l1[(size_t)m * H_ + j] = fmaxf(z, 0.f);
}

// ---------------------------------------------------------------------------
// K6: head + loss
// ---------------------------------------------------------------------------
__global__ void k_head(const float* __restrict__ l1, const float* __restrict__ W2,
                       const float* __restrict__ b2, const int* __restrict__ labels,
                       float* __restrict__ out) {
    const int tid = threadIdx.x;  // 320 threads
    __shared__ float red[320];
    float term = 0.f;
    if (tid < 320) {
        int m = tid / 5, cc = tid % 5;
        float z = b2[cc];
        for (int k = 0; k < H_; ++k) z += l1[(size_t)m * H_ + k] * W2[(size_t)k * C_ + cc];
        float p = 1.f / (1.f + expf(-z));
        out[tid] = p;
        term = -(float)labels[tid] * logf(p);
    }
    red[tid] = term;
    __syncthreads();
    if (tid == 0) {
        float s = 0.f;
        for (int i = 0; i < 320; ++i) s += red[i];
        out[320] = s / (float)C_;
    }
}

// ---------------------------------------------------------------------------
extern "C" void kernel_launch(void* const* d_in, const int* in_sizes, int n_in,
                              void* d_out, int out_size, void* d_ws, size_t ws_size,
                              hipStream_t stream) {
    const float* x      = (const float*)d_in[0];
    const float* ent    = (const float*)d_in[1];
    const int*   labels = (const int*)d_in[2];
    const float* Wfw    = (const float*)d_in[3];
    const float* bfw    = (const float*)d_in[4];
    const float* Wbw    = (const float*)d_in[5];
    const float* bbw    = (const float*)d_in[6];
    const float* W1     = (const float*)d_in[7];
    const float* b1     = (const float*)d_in[8];
    const float* W2     = (const float*)d_in[9];
    const float* b2     = (const float*)d_in[10];
    float* out = (float*)d_out;

    float*    ws     = (float*)d_ws;
    float*    xw     = ws;                          // 4,194,304 floats
    float*    lout   = xw + 4194304;                // 1,048,576 floats
    unsigned* exbuf  = (unsigned*)(lout + 1048576); // 65,536 u32 (64 groups * 4 slots * 256)
    float*    l1     = (float*)(exbuf + 65536);     // 16,384 floats
    int*      length = (int*)(l1 + 16384);          // 32 ints
    float*    partials = xw;                        // alias: xw dead after k_lstm

    k_length<<<32, 64, 0, stream>>>(x, length);
    k_xw<<<dim3(16, 32, 2), 256, 0, stream>>>(x, Wfw, bfw, Wbw, bbw, xw);
    k_lstm<<<256, 512, 0, stream>>>(Wfw, Wbw, xw, length, lout, exbuf);
    k_einsum<<<dim3(8, 32), 512, 0, stream>>>(ent, lout, partials);
    k_l1<<<64, 256, 0, stream>>>(partials, W1, b1, l1);
    k_head<<<1, 320, 0, stream>>>(l1, W2, b2, labels, out);
}

// Round 5
// 323.395 us; speedup vs baseline: 3.2802x; 1.2207x over previous
//
#include <hip/hip_runtime.h>
#include <math.h>

#define B_   32
#define T_   64
#define D_   300
#define H_   256
#define G4H  1024   // 4*H
#define M_   64
#define C_   5

typedef _Float16 h2v __attribute__((ext_vector_type(2)));
typedef _Float16 h8  __attribute__((ext_vector_type(8)));
typedef float    f4  __attribute__((ext_vector_type(4)));

__device__ __forceinline__ float sigmoidf_(float x) { return 1.0f / (1.0f + expf(-x)); }

__device__ __forceinline__ float dot2_(h2v a, h2v b, float c) {
#if __has_builtin(__builtin_amdgcn_fdot2)
    return __builtin_amdgcn_fdot2(a, b, c, false);
#else
    return c + (float)a[0] * (float)b[0] + (float)a[1] * (float)b[1];
#endif
}

// ---------------------------------------------------------------------------
// K1: length[b]
// ---------------------------------------------------------------------------
__global__ void k_length(const float* __restrict__ x, int* __restrict__ length) {
    const int b = blockIdx.x;
    const int t = threadIdx.x;  // 64 threads
    float mv = 0.f;
    const float* row = x + (size_t)(b * T_ + t) * D_;
    for (int d = 0; d < D_; ++d) mv = fmaxf(mv, fabsf(row[d]));
    unsigned long long m = __ballot(mv > 0.f);
    if (t == 0) length[b] = __popcll(m);
}

// ---------------------------------------------------------------------------
// K2: xw = x-part of gate pre-activations (+ bias). f16 MFMA GEMM.
// M=2048 (b*T rows), N=2048 (fw cols 0..1023, bw 1024..2047), K=320 (300+pad).
// 128x128 tile per block, 4 waves in 2x2, 16x16x32 mfma.
// ---------------------------------------------------------------------------
__global__ void __launch_bounds__(256)
k_xw(const float* __restrict__ x,
     const float* __restrict__ Wfw, const float* __restrict__ bfw,
     const float* __restrict__ Wbw, const float* __restrict__ bbw,
     float* __restrict__ xw) {
    const int nt  = blockIdx.x;       // 0..15 col tile
    const int mt  = blockIdx.y;       // 0..15 row tile
    const int tid = threadIdx.x;      // 256
    const int w   = tid >> 6;         // wave 0..3
    const int l   = tid & 63;
    const int n0  = nt * 128, m0 = mt * 128;
    const int dir = n0 >> 10;               // 1024%128==0: tiles don't straddle
    const float* W    = dir ? Wbw : Wfw;
    const float* bias = dir ? bbw : bfw;
    const int ncol0 = n0 & 1023;

    __shared__ __align__(16) _Float16 As[128][40];  // 32 k + 8 pad
    __shared__ __align__(16) _Float16 Bs[128][40];  // [col][k]

    f4 acc[4][4];
    #pragma unroll
    for (int i = 0; i < 4; ++i)
        #pragma unroll
        for (int j = 0; j < 4; ++j) acc[i][j] = (f4){0.f, 0.f, 0.f, 0.f};

    const int wr = (w >> 1) * 64;   // wave row quadrant
    const int wc = (w & 1) * 64;    // wave col quadrant

    for (int k0 = 0; k0 < 320; k0 += 32) {
        // stage A: rows m0..m0+127, k k0..k0+31 (lane varies k -> coalesced)
        #pragma unroll
        for (int r = 0; r < 16; ++r) {
            int row = r * 8 + (tid >> 5);
            int kk  = tid & 31;
            int k   = k0 + kk;
            As[row][kk] = (k < D_) ? (_Float16)x[(size_t)(m0 + row) * D_ + k]
                                   : (_Float16)0.f;
        }
        // stage B: cols n0..n0+127, k k0..k0+31 (lane varies col -> coalesced)
        #pragma unroll
        for (int r = 0; r < 16; ++r) {
            int col = (tid & 31) + (r & 3) * 32;
            int kk  = (tid >> 5) + (r >> 2) * 8;
            int k   = k0 + kk;
            Bs[col][kk] = (k < D_) ? (_Float16)W[(size_t)k * G4H + ncol0 + col]
                                   : (_Float16)0.f;
        }
        __syncthreads();

        h8 afr[4], bfr[4];
        #pragma unroll
        for (int fr = 0; fr < 4; ++fr)
            afr[fr] = *(const h8*)&As[wr + fr * 16 + (l & 15)][(l >> 4) * 8];
        #pragma unroll
        for (int fc = 0; fc < 4; ++fc)
            bfr[fc] = *(const h8*)&Bs[wc + fc * 16 + (l & 15)][(l >> 4) * 8];
        #pragma unroll
        for (int fr = 0; fr < 4; ++fr)
            #pragma unroll
            for (int fc = 0; fc < 4; ++fc)
                acc[fr][fc] = __builtin_amdgcn_mfma_f32_16x16x32_f16(
                    afr[fr], bfr[fc], acc[fr][fc], 0, 0, 0);
        __syncthreads();
    }

    // epilogue: D[row][col]: col = l&15, row = (l>>4)*4 + e  (m89-verified)
    #pragma unroll
    for (int fc = 0; fc < 4; ++fc) {
        int col = ncol0 + wc + fc * 16 + (l & 15);
        float bv = bias[col];
        #pragma unroll
        for (int fr = 0; fr < 4; ++fr) {
            #pragma unroll
            for (int e = 0; e < 4; ++e) {
                int row = m0 + wr + fr * 16 + (l >> 4) * 4 + e;
                xw[(size_t)dir * 2048 * G4H + (size_t)row * G4H + col] =
                    acc[fr][fc][e] + bv;
            }
        }
    }
}

// ---------------------------------------------------------------------------
// K3: LSTM recurrence. 256 blocks = 64 groups (dir,b) x 4 column-slices.
// W_h column held in REGISTERS as f16 pairs (64 h2v per thread; thread owns
// gate-col c = w*32+(l&31), k-half = l>>5). Dot via v_dot2_f32_f16, combined
// with one shfl_xor(32). Cross-block h exchange: tagged-data protocol
// (fp32 LSB = ring-cycle parity, relaxed agent atomics, 4-slot ring) —
// unchanged from the round-4 kernel that validated at absmax 0.0039.
// ---------------------------------------------------------------------------
__global__ void __launch_bounds__(512)
k_lstm(const float* __restrict__ Wfw, const float* __restrict__ Wbw,
       const float* __restrict__ xw, const int* __restrict__ length,
       float* __restrict__ lout, unsigned* __restrict__ exbuf) {
    const int bid = blockIdx.x;
    const int js  = bid >> 6;        // 0..3 column slice
    const int g   = bid & 63;        // group id
    const int dir = g >> 5;
    const int b   = g & 31;
    const int tid = threadIdx.x;     // 0..511
    const int w   = tid >> 6;        // wave 0..7
    const int l   = tid & 63;
    const int c     = w * 32 + (l & 31);   // gate-col 0..255 (gate = c>>6, jj = c&63)
    const int khalf = l >> 5;              // 0: k 0..127, 1: k 128..255
    const int colg  = (c >> 6) * 256 + js * 64 + (c & 63);

    __shared__ __align__(8) _Float16 hl_h[256];
    __shared__ float zfin[256];

    const float* Wg = dir ? Wbw : Wfw;

    // ---- stage this thread's W_h column-half into registers (f16 pairs) ----
    h2v wreg[64];
    #pragma unroll
    for (int p = 0; p < 64; ++p) {
        int k = khalf * 128 + 2 * p;
        float w0 = Wg[(size_t)(D_ + k) * G4H + colg];
        float w1 = Wg[(size_t)(D_ + k + 1) * G4H + colg];
        h2v t; t[0] = (_Float16)w0; t[1] = (_Float16)w1;
        wreg[p] = t;
    }

    if (tid < 256) hl_h[tid] = (_Float16)0.f;
    const int len = length[b];
    const size_t xrow = (size_t)(dir * B_ + b) * T_;
    __syncthreads();

    float cst = 0.f, hprev = 0.f;

    for (int s = 0; s < T_; ++s) {
        const int tt = dir ? (T_ - 1 - s) : s;
        const unsigned tag = ((unsigned)(s >> 2) & 1u) ^ 1u;   // ring-cycle parity
        const size_t slotBase = ((size_t)g * 4 + (s & 3)) * 256;

        // x-part (issued early; consumed at zfin write)
        float xv = 0.f;
        if (l < 32) xv = xw[(xrow + tt) * G4H + colg];

        // ---- dot: this col, this k-half: 32 broadcast b64 reads + 64 fdot2 ----
        float acc = 0.f;
        const uint2* hp = (const uint2*)&hl_h[khalf * 128];
        #pragma unroll
        for (int j = 0; j < 32; ++j) {
            uint2 hv = hp[j];
            acc = dot2_(wreg[2 * j],     __builtin_bit_cast(h2v, hv.x), acc);
            acc = dot2_(wreg[2 * j + 1], __builtin_bit_cast(h2v, hv.y), acc);
        }
        acc += __shfl_xor(acc, 32);          // combine the two k-halves
        if (l < 32) zfin[c] = acc + xv;
        __syncthreads();

        // ---- gates for this block's 64 h-columns; publish tagged h slice ----
        if (tid < 64) {
            float zi = zfin[tid], zj = zfin[64 + tid], zf = zfin[128 + tid], zo = zfin[192 + tid];
            float cn = sigmoidf_(zf + 1.0f) * cst + sigmoidf_(zi) * tanhf(zj);
            float hn = sigmoidf_(zo) * tanhf(cn);
            bool  msk = (tt < len);
            float ho  = msk ? hn : 0.f;
            float hk2 = msk ? hn : hprev;
            if (msk) cst = cn;
            hprev = hk2;
            int jglob = js * 64 + tid;
            lout[((size_t)(b * T_ + tt)) * (2 * H_) + dir * H_ + jglob] = ho;
            hl_h[jglob] = (_Float16)hk2;     // own slice straight into LDS
            unsigned bits = (__float_as_uint(hk2) & ~1u) | tag;
            __hip_atomic_store(&exbuf[slotBase + jglob], bits,
                               __ATOMIC_RELAXED, __HIP_MEMORY_SCOPE_AGENT);
        }

        // ---- poll peers' tagged words (single L3 trip, relaxed) ----
        if (tid < 256 && (tid >> 6) != js) {
            unsigned v; unsigned it = 0;
            for (;;) {
                v = __hip_atomic_load(&exbuf[slotBase + tid],
                                      __ATOMIC_RELAXED, __HIP_MEMORY_SCOPE_AGENT);
                if ((v & 1u) == tag) break;
                __builtin_amdgcn_s_sleep(1);
                if (++it > (1u << 20)) break;   // safety valve: wrong > wedged
            }
            hl_h[tid] = (_Float16)__uint_as_float(v);
        }
        __syncthreads();
    }
}

// ---------------------------------------------------------------------------
// K4: einsum partials. Grid (8 m-groups, 32 b). lout[b] staged in LDS once;
// ent streamed (the mandatory 268 MB of HBM).
// ---------------------------------------------------------------------------
__global__ void __launch_bounds__(512)
k_einsum(const float* __restrict__ ent, const float* __restrict__ lout,
         float* __restrict__ partials) {
    const int mg = blockIdx.x;   // 0..7
    const int b  = blockIdx.y;   // 0..31
    const int d  = threadIdx.x;  // 0..511

    __shared__ float louts[T_][512];
    for (int t = 0; t < T_; ++t) louts[t][d] = lout[((size_t)(b * T_ + t)) * 512 + d];
    __syncthreads();

    for (int mi = 0; mi < 8; ++mi) {
        int m = mg * 8 + mi;
        const float* ep = ent + ((size_t)(m * B_ + b) * T_) * 512 + d;
        float acc = 0.f;
        #pragma unroll 4
        for (int t = 0; t < T_; ++t) acc += ep[(size_t)t * 512] * louts[t][d];
        partials[((size_t)m * B_ + b) * 512 + d] = acc;
    }
}

// ---------------------------------------------------------------------------
// K5: reduce partials over b -> output_f, then l1 = relu(of @ W1 + b1)
// ---------------------------------------------------------------------------
__global__ void k_l1(const float* __restrict__ partials, const float* __restrict__ W1,
                     const float* __restrict__ b1, float* __restrict__ l1) {
    const int m = blockIdx.x;
    const int j = threadIdx.x;  // 0..255
    __shared__ float of[512];
    for (int d = j; d < 512; d += 256) {
        float s = 0.f;
        #pragma unroll
        for (int cc = 0; cc < 32; ++cc) s += partials[((size_t)m * B_ + cc) * 512 + d];
        of[d] = s * (1.0f / T_);
    }
    __syncthreads();
    float z = b1[j];
    for (int k = 0; k < 512; ++k) z += of[k] * W1[(size_t)k * H_ + j];
    l1[(size_t)m * H_ + j] = fmaxf(z, 0.f);
}

// ---------------------------------------------------------------------------
// K6: head + loss
// ---------------------------------------------------------------------------
__global__ void k_head(const float* __restrict__ l1, const float* __restrict__ W2,
                       const float* __restrict__ b2, const int* __restrict__ labels,
                       float* __restrict__ out) {
    const int tid = threadIdx.x;  // 320 threads
    __shared__ float red[320];
    float term = 0.f;
    if (tid < 320) {
        int m = tid / 5, cc = tid % 5;
        float z = b2[cc];
        for (int k = 0; k < H_; ++k) z += l1[(size_t)m * H_ + k] * W2[(size_t)k * C_ + cc];
        float p = 1.f / (1.f + expf(-z));
        out[tid] = p;
        term = -(float)labels[tid] * logf(p);
    }
    red[tid] = term;
    __syncthreads();
    if (tid == 0) {
        float s = 0.f;
        for (int i = 0; i < 320; ++i) s += red[i];
        out[320] = s / (float)C_;
    }
}

// ---------------------------------------------------------------------------
extern "C" void kernel_launch(void* const* d_in, const int* in_sizes, int n_in,
                              void* d_out, int out_size, void* d_ws, size_t ws_size,
                              hipStream_t stream) {
    const float* x      = (const float*)d_in[0];
    const float* ent    = (const float*)d_in[1];
    const int*   labels = (const int*)d_in[2];
    const float* Wfw    = (const float*)d_in[3];
    const float* bfw    = (const float*)d_in[4];
    const float* Wbw    = (const float*)d_in[5];
    const float* bbw    = (const float*)d_in[6];
    const float* W1     = (const float*)d_in[7];
    const float* b1     = (const float*)d_in[8];
    const float* W2     = (const float*)d_in[9];
    const float* b2     = (const float*)d_in[10];
    float* out = (float*)d_out;

    float*    ws     = (float*)d_ws;
    float*    xw     = ws;                          // 4,194,304 floats
    float*    lout   = xw + 4194304;                // 1,048,576 floats
    unsigned* exbuf  = (unsigned*)(lout + 1048576); // 65,536 u32 (64 groups * 4 slots * 256)
    float*    l1     = (float*)(exbuf + 65536);     // 16,384 floats
    int*      length = (int*)(l1 + 16384);          // 32 ints
    float*    partials = xw;                        // alias: xw dead after k_lstm

    k_length<<<32, 64, 0, stream>>>(x, length);
    k_xw<<<dim3(16, 16), 256, 0, stream>>>(x, Wfw, bfw, Wbw, bbw, xw);
    k_lstm<<<256, 512, 0, stream>>>(Wfw, Wbw, xw, length, lout, exbuf);
    k_einsum<<<dim3(8, 32), 512, 0, stream>>>(ent, lout, partials);
    k_l1<<<64, 256, 0, stream>>>(partials, W1, b1, l1);
    k_head<<<1, 320, 0, stream>>>(l1, W2, b2, labels, out);
}